// Round 4
// baseline (120.626 us; speedup 1.0000x reference)
//
#include <hip/hip_runtime.h>
#include <stdint.h>

// Segmented kNN graph: M=65536 pts, D=16, 64 segments x 1024 pts, K=16.
// Output: int32 src[M*16] then int32 dst[M*16].
//
// v3b: occupancy-first. mfma_f32_16x16x16f16 (K=16 exact, no pad lanes);
// A-fragments streamed from global (L2-resident, wave's loads = contiguous
// 1KB); LDS only 4KB |c|^2 + 2KB merge buf -> 8 blocks/CU, 32 waves/CU.
// Block = 2 query-groups x 2 candidate-halves; cross-wave merge via LDS.
// Keys: float bits of (|c|^2+128-2dot) truncated to 22 bits + 10-bit idx;
// bias keeps kf>0 so raw float bits are order-preserving (no sign fixup).
// Selection: Batcher odd-even mergesort-16 (63 CE) + bitonic half-merge.
// (v3 -> v3b: __fp16 vector types to match cvt_pkrtz/mfma builtin sigs.)

#define L_SEG 1024
#define M_PTS 65536

typedef __fp16 fp16x2 __attribute__((ext_vector_type(2)));
typedef __fp16 fp16x4 __attribute__((ext_vector_type(4)));
typedef float  f32x4  __attribute__((ext_vector_type(4)));

__device__ __forceinline__ uint32_t umn(uint32_t a, uint32_t b) { return a < b ? a : b; }
__device__ __forceinline__ uint32_t umx(uint32_t a, uint32_t b) { return a > b ? a : b; }

__device__ __forceinline__ fp16x4 pack4(float a, float b, float c, float d) {
    union { fp16x2 h2[2]; fp16x4 h4; } u;
    u.h2[0] = __builtin_amdgcn_cvt_pkrtz(a, b);
    u.h2[1] = __builtin_amdgcn_cvt_pkrtz(c, d);
    return u.h4;
}

// bitonic clean of 16 (input bitonic, output sorted ascending)
__device__ __forceinline__ void clean16(uint32_t* A) {
    #pragma unroll
    for (int j = 8; j > 0; j >>= 1) {
        #pragma unroll
        for (int i = 0; i < 16; ++i) {
            int p = i ^ j;
            if (p > i) {
                uint32_t lo = umn(A[i], A[p]);
                uint32_t hi = umx(A[i], A[p]);
                A[i] = lo; A[p] = hi;
            }
        }
    }
}

__global__ __launch_bounds__(256, 8) void knn_stream_kernel(const float* __restrict__ x,
                                                            int* __restrict__ out) {
    __shared__ float    ssq[L_SEG];          // |c~|^2 + 128 (f16-rounded coords)
    __shared__ uint32_t sbuf[2][16][17];     // cross-wave merge buffer (padded)

    const int tid = threadIdx.x;
    const int b   = blockIdx.x;
    const int seg = b >> 5;
    const int qp  = b & 31;
    const float* xseg = x + (size_t)seg * (L_SEG * 16);

    // ---- stage biased squared norms (4 candidates per thread) ----
    {
        const int c0 = tid << 2;
        #pragma unroll
        for (int c = 0; c < 4; ++c) {
            const float* px = xseg + (size_t)(c0 + c) * 16;
            float s = 128.0f;
            #pragma unroll
            for (int d = 0; d < 16; d += 2) {
                fp16x2 hh = __builtin_amdgcn_cvt_pkrtz(px[d], px[d + 1]);
                float f0 = (float)hh[0], f1 = (float)hh[1];
                s = __builtin_fmaf(f0, f0, s);
                s = __builtin_fmaf(f1, f1, s);
            }
            ssq[c0 + c] = s;
        }
    }
    __syncthreads();

    const int lane = tid & 63;
    const int w    = tid >> 6;
    const int qg   = w >> 1;     // query group within block (0..1)
    const int h    = w & 1;      // candidate half (0..1)
    const int g    = lane >> 4;  // k-quad / D-row group
    const int col  = lane & 15;
    const int qloc = qp * 32 + qg * 16 + col;
    const int qglob = seg * L_SEG + qloc;

    // B fragment: query col's dims 4g..4g+3 as f16
    fp16x4 bfrag;
    {
        const float* bq = x + (size_t)qglob * 16 + g * 4;
        bfrag = pack4(bq[0], bq[1], bq[2], bq[3]);
    }

    uint32_t A[16];
    #pragma unroll
    for (int i = 0; i < 16; ++i) A[i] = 0xFFFFFFFFu;

    // A-fragment stream: lane supplies candidate (tilebase+col), dims 4g..4g+3
    const float* abase = xseg + (size_t)(h * 512 + col) * 16 + g * 4;
    const int hb = h * 512;

    #pragma unroll 2
    for (int t0 = 0; t0 < 8; ++t0) {
        uint32_t B[16];
        #pragma unroll
        for (int tt = 0; tt < 4; ++tt) {
            const int tb = t0 * 64 + tt * 16;  // tile base within this half
            const float* ap = abase + (size_t)tb * 16;
            fp16x4 af = pack4(ap[0], ap[1], ap[2], ap[3]);
            f32x4 z = {0.f, 0.f, 0.f, 0.f};
            f32x4 acc = __builtin_amdgcn_mfma_f32_16x16x16f16(af, bfrag, z, 0, 0, 0);
            const f32x4 sq = *(const f32x4*)&ssq[hb + tb + g * 4];
            const uint32_t idxt = (uint32_t)(hb + tb + g * 4);
            #pragma unroll
            for (int v = 0; v < 4; ++v) {
                float kf = __builtin_fmaf(acc[v], -2.0f, sq[v]);  // d2 - |q|^2 + 128 > 0
                uint32_t u = __float_as_uint(kf) & 0xFFFFFC00u;
                B[tt * 4 + v] = u + idxt + (uint32_t)v;           // low 10 bits = cand idx
            }
        }
        // Batcher odd-even mergesort-16, ascending (63 CEs, compile-time unrolled)
        #pragma unroll
        for (int p = 1; p < 16; p <<= 1) {
            #pragma unroll
            for (int k = p; k >= 1; k >>= 1) {
                #pragma unroll
                for (int j = (k & (p - 1)); j + k < 16; j += 2 * k) {
                    #pragma unroll
                    for (int i = 0; i <= ((k - 1 < 15 - j - k) ? k - 1 : 15 - j - k); ++i) {
                        if ((i + j) / (2 * p) == (i + j + k) / (2 * p)) {
                            uint32_t lo = umn(B[i + j], B[i + j + k]);
                            uint32_t hi = umx(B[i + j], B[i + j + k]);
                            B[i + j] = lo; B[i + j + k] = hi;
                        }
                    }
                }
            }
        }
        // merge sorted B into sorted A, keep lowest 16
        #pragma unroll
        for (int i = 0; i < 16; ++i) A[i] = umn(A[i], B[15 - i]);
        clean16(A);
    }

    // in-wave merges: lanes xor 16, 32 (same query, disjoint candidate rows)
    #pragma unroll
    for (int m = 16; m <= 32; m <<= 1) {
        uint32_t P[16];
        #pragma unroll
        for (int i = 0; i < 16; ++i) P[i] = (uint32_t)__shfl_xor((int)A[15 - i], m, 64);
        #pragma unroll
        for (int i = 0; i < 16; ++i) A[i] = umn(A[i], P[i]);
        clean16(A);
    }

    // cross-wave merge: half 1 publishes, half 0 merges + writes out
    if (h == 1) {
        #pragma unroll
        for (int v = 0; v < 4; ++v) sbuf[qg][col][g * 4 + v] = A[g * 4 + v];
    }
    __syncthreads();
    if (h == 0) {
        uint32_t P[16];
        #pragma unroll
        for (int i = 0; i < 16; ++i) P[i] = sbuf[qg][col][15 - i];
        #pragma unroll
        for (int i = 0; i < 16; ++i) A[i] = umn(A[i], P[i]);
        clean16(A);

        const int base = seg * L_SEG;
        const int q    = qglob;
        uint32_t r[4];
        #pragma unroll
        for (int v = 0; v < 4; ++v) {  // static select of A[4g+v]
            uint32_t t01 = (g & 1) ? A[4 + v]  : A[v];
            uint32_t t23 = (g & 1) ? A[12 + v] : A[8 + v];
            r[v] = (g & 2) ? t23 : t01;
        }
        int4 sv;
        sv.x = base + (int)(r[0] & 1023u);
        sv.y = base + (int)(r[1] & 1023u);
        sv.z = base + (int)(r[2] & 1023u);
        sv.w = base + (int)(r[3] & 1023u);
        ((int4*)out)[(size_t)q * 4 + g] = sv;
        ((int4*)out)[(size_t)M_PTS * 4 + (size_t)q * 4 + g] = make_int4(q, q, q, q);
    }
}

extern "C" void kernel_launch(void* const* d_in, const int* in_sizes, int n_in,
                              void* d_out, int out_size, void* d_ws, size_t ws_size,
                              hipStream_t stream) {
    const float* x = (const float*)d_in[0];
    // d_in[1] = segs (int64, all 1024) — static per problem setup, unused.
    int* out = (int*)d_out;
    (void)d_ws; (void)ws_size;
    knn_stream_kernel<<<dim3(2048), dim3(256), 0, stream>>>(x, out);
}

// Round 5
// 92.358 us; speedup vs baseline: 1.3061x; 1.3061x over previous
//
#include <hip/hip_runtime.h>
#include <stdint.h>

// Segmented kNN graph: M=65536 pts, D=16, 64 segments x 1024 pts, K=16.
// Output: int32 src[M*16] then int32 dst[M*16].
//
// v5 = round-2 memory structure (LDS-staged f16 coords; global streaming in
// round 4 thrashed L2: FETCH 2->37MB, VALUBusy 64->47%) + round-4 arithmetic:
// mfma_f32_16x16x16f16 (K=16 exact, no zero-pad lanes), +128-biased keys
// (raw float bits order-preserving, and_or pack), Batcher sort-16 batches
// merged into a sorted top-16. Each wave owns 16 queries x all 1024
// candidates -> no cross-wave merge. 1024 blocks (16/seg, XCD-swizzled),
// 36KB LDS -> 4 blocks/CU.

#define L_SEG 1024
#define M_PTS 65536

typedef __fp16 fp16x2 __attribute__((ext_vector_type(2)));
typedef __fp16 fp16x4 __attribute__((ext_vector_type(4)));
typedef float  f32x4  __attribute__((ext_vector_type(4)));

__device__ __forceinline__ uint32_t umn(uint32_t a, uint32_t b) { return a < b ? a : b; }
__device__ __forceinline__ uint32_t umx(uint32_t a, uint32_t b) { return a > b ? a : b; }

// bitonic clean of 16 (input bitonic, output sorted ascending): 32 CEs
__device__ __forceinline__ void clean16(uint32_t* A) {
    #pragma unroll
    for (int j = 8; j > 0; j >>= 1) {
        #pragma unroll
        for (int i = 0; i < 16; ++i) {
            int p = i ^ j;
            if (p > i) {
                uint32_t lo = umn(A[i], A[p]);
                uint32_t hi = umx(A[i], A[p]);
                A[i] = lo; A[p] = hi;
            }
        }
    }
}

__global__ __launch_bounds__(256, 4) void knn_v5_kernel(const float* __restrict__ x,
                                                        int* __restrict__ out) {
    __shared__ __attribute__((aligned(16))) __fp16 sc[L_SEG * 16];  // 32 KB f16 coords
    __shared__ __attribute__((aligned(16))) float  ssq[L_SEG];      // |c~|^2 + 128

    const int tid = threadIdx.x;
    const int b   = blockIdx.x;
    // bijective: seg = lo*8+hi, qp = mid  (lo=b&7 ~ XCD id -> one XCD covers 8 segs)
    const int seg = (b & 7) * 8 + (b >> 7);
    const int qp  = (b >> 3) & 15;
    const float* xseg = x + (size_t)seg * (L_SEG * 16);

    // ---- stage f16 coords (coalesced f32x4 global loads, contiguous 8B LDS writes) ----
    {
        const f32x4* gx  = (const f32x4*)xseg;
        fp16x4*      scv = (fp16x4*)sc;
        #pragma unroll
        for (int i = 0; i < 16; ++i) {
            f32x4 v = gx[tid + 256 * i];
            union { fp16x2 h2[2]; fp16x4 h4; } u;
            u.h2[0] = __builtin_amdgcn_cvt_pkrtz(v[0], v[1]);
            u.h2[1] = __builtin_amdgcn_cvt_pkrtz(v[2], v[3]);
            scv[tid + 256 * i] = u.h4;
        }
    }
    __syncthreads();

    // ---- biased squared norms from the f16-rounded coords (match MFMA dots) ----
    {
        const int r0 = tid << 2;
        #pragma unroll
        for (int c = 0; c < 4; ++c) {
            const fp16x2* hp = (const fp16x2*)(sc + (size_t)(r0 + c) * 16);
            float s = 128.0f;
            #pragma unroll
            for (int j = 0; j < 8; ++j) {
                fp16x2 hh = hp[j];
                float f0 = (float)hh[0], f1 = (float)hh[1];
                s = __builtin_fmaf(f0, f0, s);
                s = __builtin_fmaf(f1, f1, s);
            }
            ssq[r0 + c] = s;
        }
    }
    __syncthreads();

    const int lane = tid & 63;
    const int w    = tid >> 6;
    const int g    = lane >> 4;   // k-quad / candidate-row group
    const int col  = lane & 15;   // this lane's query column
    const int qloc = qp * 64 + w * 16 + col;

    // B fragment: query qloc, dims 4g..4g+3 (8B LDS read, once)
    const fp16x4 bfrag = *(const fp16x4*)(sc + (size_t)qloc * 16 + g * 4);

    uint32_t A[16];
    #pragma unroll
    for (int i = 0; i < 16; ++i) A[i] = 0xFFFFFFFFu;

    const __fp16* ap0 = sc + (size_t)col * 16 + g * 4;

    for (int t0 = 0; t0 < 16; ++t0) {  // 16 batches x 4 tiles x 16 cands
        uint32_t B[16];
        #pragma unroll
        for (int tt = 0; tt < 4; ++tt) {
            const int tb = t0 * 64 + tt * 16;
            fp16x4 af = *(const fp16x4*)(ap0 + (size_t)tb * 16);
            f32x4 z = {0.f, 0.f, 0.f, 0.f};
            f32x4 acc = __builtin_amdgcn_mfma_f32_16x16x16f16(af, bfrag, z, 0, 0, 0);
            const f32x4 sq = *(const f32x4*)&ssq[tb + g * 4];
            const uint32_t idxt = (uint32_t)(tb + g * 4);
            #pragma unroll
            for (int v = 0; v < 4; ++v) {
                float kf = __builtin_fmaf(acc[v], -2.0f, sq[v]);  // d2 - |q|^2 + 128 > 0
                B[tt * 4 + v] = (__float_as_uint(kf) & 0xFFFFFC00u) | (idxt + (uint32_t)v);
            }
        }
        // Batcher odd-even mergesort-16, ascending (63 CEs)
        #pragma unroll
        for (int p = 1; p < 16; p <<= 1) {
            #pragma unroll
            for (int k = p; k >= 1; k >>= 1) {
                #pragma unroll
                for (int j = (k & (p - 1)); j + k < 16; j += 2 * k) {
                    #pragma unroll
                    for (int i = 0; i <= ((k - 1 < 15 - j - k) ? k - 1 : 15 - j - k); ++i) {
                        if ((i + j) / (2 * p) == (i + j + k) / (2 * p)) {
                            uint32_t lo = umn(B[i + j], B[i + j + k]);
                            uint32_t hi = umx(B[i + j], B[i + j + k]);
                            B[i + j] = lo; B[i + j + k] = hi;
                        }
                    }
                }
            }
        }
        // merge sorted B into sorted A, keep lowest 16
        #pragma unroll
        for (int i = 0; i < 16; ++i) A[i] = umn(A[i], B[15 - i]);
        clean16(A);
    }

    // in-wave merges: lanes xor 16, 32 (same query, disjoint candidate rows)
    #pragma unroll
    for (int m = 16; m <= 32; m <<= 1) {
        uint32_t P[16];
        #pragma unroll
        for (int i = 0; i < 16; ++i) P[i] = (uint32_t)__shfl_xor((int)A[15 - i], m, 64);
        #pragma unroll
        for (int i = 0; i < 16; ++i) A[i] = umn(A[i], P[i]);
        clean16(A);
    }

    // Epilogue: lane (g,col) writes int4 #g of src and dst for its query.
    const int base = seg * L_SEG;
    const int q    = base + qloc;
    uint32_t r[4];
    #pragma unroll
    for (int v = 0; v < 4; ++v) {  // static select of A[4g+v]
        uint32_t t01 = (g & 1) ? A[4 + v]  : A[v];
        uint32_t t23 = (g & 1) ? A[12 + v] : A[8 + v];
        r[v] = (g & 2) ? t23 : t01;
    }
    int4 sv;
    sv.x = base + (int)(r[0] & 1023u);
    sv.y = base + (int)(r[1] & 1023u);
    sv.z = base + (int)(r[2] & 1023u);
    sv.w = base + (int)(r[3] & 1023u);
    ((int4*)out)[(size_t)q * 4 + g] = sv;
    ((int4*)out)[(size_t)M_PTS * 4 + (size_t)q * 4 + g] = make_int4(q, q, q, q);
}

extern "C" void kernel_launch(void* const* d_in, const int* in_sizes, int n_in,
                              void* d_out, int out_size, void* d_ws, size_t ws_size,
                              hipStream_t stream) {
    const float* x = (const float*)d_in[0];
    // d_in[1] = segs (int64, all 1024) — static per problem setup, unused.
    int* out = (int*)d_out;
    (void)d_ws; (void)ws_size;
    knn_v5_kernel<<<dim3(1024), dim3(256), 0, stream>>>(x, out);
}

// Round 6
// 92.050 us; speedup vs baseline: 1.3104x; 1.0033x over previous
//
#include <hip/hip_runtime.h>
#include <stdint.h>

// Segmented kNN graph: M=65536 pts, D=16, 64 segments x 1024 pts, K=16.
// Output: int32 src[M*16] then int32 dst[M*16].
//
// v6 = v5 + stall removal:
//  - fragment-ready LDS layout: A-frags stored [batch][half][lane] as 16B
//    entries -> 2 contiguous ds_read_b128/batch (v5: 4 strided ds_read_b64,
//    4-way bank conflicts, SQ_LDS_BANK_CONFLICT=4.07M).
//  - coords stored scaled by -2 (exact in f16); norms (+128 bias) fed as the
//    MFMA C operand -> key pack is a single v_and_or per key (v5: fma+and_or).
//  - queries kept in a separate unscaled f16 array (2KB).
//  - explicit next-batch prefetch to hide ds_read latency under the sort.
// LDS 38KB -> 4 blocks/CU (grid 1024 = 4 blocks/CU anyway).

#define L_SEG 1024
#define M_PTS 65536

typedef __fp16 fp16x2 __attribute__((ext_vector_type(2)));
typedef __fp16 fp16x4 __attribute__((ext_vector_type(4)));
typedef float  f32x4  __attribute__((ext_vector_type(4)));

__device__ __forceinline__ uint32_t umn(uint32_t a, uint32_t b) { return a < b ? a : b; }
__device__ __forceinline__ uint32_t umx(uint32_t a, uint32_t b) { return a > b ? a : b; }

// bitonic clean of 16 (input bitonic, output sorted ascending): 32 CEs
__device__ __forceinline__ void clean16(uint32_t* A) {
    #pragma unroll
    for (int j = 8; j > 0; j >>= 1) {
        #pragma unroll
        for (int i = 0; i < 16; ++i) {
            int p = i ^ j;
            if (p > i) {
                uint32_t lo = umn(A[i], A[p]);
                uint32_t hi = umx(A[i], A[p]);
                A[i] = lo; A[p] = hi;
            }
        }
    }
}

__global__ __launch_bounds__(256, 4) void knn_v6_kernel(const float* __restrict__ x,
                                                        int* __restrict__ out) {
    // sfrag: 16 batches x 2KB. byte(batch,tt,g,col) =
    //   batch*2048 + (tt>>1)*1024 + (g*16+col)*16 + (tt&1)*8
    __shared__ __attribute__((aligned(16))) __fp16 sfrag[16384];  // 32 KB, holds -2*c (f16)
    __shared__ __attribute__((aligned(16))) float  ssq[L_SEG];    // |c|^2 + 128 (f32)
    __shared__ __attribute__((aligned(16))) __fp16 sq16[64 * 16]; // this block's queries, f16

    const int tid = threadIdx.x;
    const int b   = blockIdx.x;
    // bijective: seg = lo*8+hi (lo=b&7 ~ XCD id -> one XCD covers 8 segs)
    const int seg = (b & 7) * 8 + (b >> 7);
    const int qp  = (b >> 3) & 15;
    const float* xseg = x + (size_t)seg * (L_SEG * 16);
    const f32x4* gx4  = (const f32x4*)xseg;

    // ---- stage A-frags: coords * -2, fragment-ready layout ----
    {
        fp16x4* fr = (fp16x4*)sfrag;  // 8-B entries, entry index F -> byte F*8
        #pragma unroll
        for (int i = 0; i < 16; ++i) {
            const int F    = i * 256 + tid;
            const int bat  = F >> 8;
            const int half = (F >> 7) & 1;
            const int e    = (F >> 1) & 63;
            const int lo   = F & 1;
            const int tt   = half * 2 + lo;
            const int g    = e >> 4;
            const int col  = e & 15;
            const int cand = bat * 64 + tt * 16 + col;
            f32x4 v = gx4[cand * 4 + g];
            union { fp16x2 h2[2]; fp16x4 h4; } u;
            u.h2[0] = __builtin_amdgcn_cvt_pkrtz(-2.0f * v[0], -2.0f * v[1]);
            u.h2[1] = __builtin_amdgcn_cvt_pkrtz(-2.0f * v[2], -2.0f * v[3]);
            fr[F] = u.h4;
        }
    }
    // ---- stage biased norms (f32, from global) ----
    {
        const int c0 = tid << 2;
        #pragma unroll
        for (int c = 0; c < 4; ++c) {
            float s = 128.0f;
            #pragma unroll
            for (int d = 0; d < 4; ++d) {
                f32x4 v = gx4[(c0 + c) * 4 + d];
                s = __builtin_fmaf(v[0], v[0], s);
                s = __builtin_fmaf(v[1], v[1], s);
                s = __builtin_fmaf(v[2], v[2], s);
                s = __builtin_fmaf(v[3], v[3], s);
            }
            ssq[c0 + c] = s;
        }
    }
    // ---- stage this block's 64 queries (unscaled f16) ----
    if (tid < 64) {
        const f32x4* qg = gx4 + (size_t)(qp * 64 + tid) * 4;
        fp16x4* dst = (fp16x4*)(sq16 + (size_t)tid * 16);
        #pragma unroll
        for (int d = 0; d < 4; ++d) {
            f32x4 v = qg[d];
            union { fp16x2 h2[2]; fp16x4 h4; } u;
            u.h2[0] = __builtin_amdgcn_cvt_pkrtz(v[0], v[1]);
            u.h2[1] = __builtin_amdgcn_cvt_pkrtz(v[2], v[3]);
            dst[d] = u.h4;
        }
    }
    __syncthreads();

    const int lane = tid & 63;
    const int w    = tid >> 6;
    const int g    = lane >> 4;   // candidate-row group
    const int col  = lane & 15;   // this lane's query column
    const int qloc = qp * 64 + w * 16 + col;

    // B fragment: query (w*16+col), dims 4g..4g+3, unscaled
    const fp16x4 bfrag = *(const fp16x4*)(sq16 + (size_t)(w * 16 + col) * 16 + g * 4);

    uint32_t A[16];
    #pragma unroll
    for (int i = 0; i < 16; ++i) A[i] = 0xFFFFFFFFu;

    const char* fb = (const char*)sfrag;
    const int   lb = lane * 16;

    union F2H { f32x4 v; fp16x4 h[2]; };
    F2H cur01, cur23;
    cur01.v = *(const f32x4*)(fb + lb);          // batch 0, tt0/tt1
    cur23.v = *(const f32x4*)(fb + 1024 + lb);   // batch 0, tt2/tt3

    for (int t0 = 0; t0 < 16; ++t0) {
        // prefetch next batch's A-frags (wraps to batch 0 at the end, harmless)
        const int nb = ((t0 + 1) & 15) * 2048;
        F2H nxt01, nxt23;
        nxt01.v = *(const f32x4*)(fb + nb + lb);
        nxt23.v = *(const f32x4*)(fb + nb + 1024 + lb);

        uint32_t B[16];
        #pragma unroll
        for (int tt = 0; tt < 4; ++tt) {
            const int tb = t0 * 64 + tt * 16;
            const f32x4 sq = *(const f32x4*)&ssq[tb + g * 4];          // broadcast read
            fp16x4 af = (tt < 2) ? cur01.h[tt] : cur23.h[tt - 2];
            // acc[v] = |c|^2 + 128 - 2*<c,q>  (C operand carries the norm+bias)
            f32x4 acc = __builtin_amdgcn_mfma_f32_16x16x16f16(af, bfrag, sq, 0, 0, 0);
            const uint32_t idxt = (uint32_t)(tb + g * 4);
            #pragma unroll
            for (int v = 0; v < 4; ++v)
                B[tt * 4 + v] = (__float_as_uint(acc[v]) & 0xFFFFFC00u) | (idxt + (uint32_t)v);
        }
        // Batcher odd-even mergesort-16, ascending (63 CEs)
        #pragma unroll
        for (int p = 1; p < 16; p <<= 1) {
            #pragma unroll
            for (int k = p; k >= 1; k >>= 1) {
                #pragma unroll
                for (int j = (k & (p - 1)); j + k < 16; j += 2 * k) {
                    #pragma unroll
                    for (int i = 0; i <= ((k - 1 < 15 - j - k) ? k - 1 : 15 - j - k); ++i) {
                        if ((i + j) / (2 * p) == (i + j + k) / (2 * p)) {
                            uint32_t lo = umn(B[i + j], B[i + j + k]);
                            uint32_t hi = umx(B[i + j], B[i + j + k]);
                            B[i + j] = lo; B[i + j + k] = hi;
                        }
                    }
                }
            }
        }
        // merge sorted B into sorted A, keep lowest 16
        #pragma unroll
        for (int i = 0; i < 16; ++i) A[i] = umn(A[i], B[15 - i]);
        clean16(A);

        cur01 = nxt01; cur23 = nxt23;
    }

    // in-wave merges: lanes xor 16, 32 (same query, disjoint candidate rows)
    #pragma unroll
    for (int m = 16; m <= 32; m <<= 1) {
        uint32_t P[16];
        #pragma unroll
        for (int i = 0; i < 16; ++i) P[i] = (uint32_t)__shfl_xor((int)A[15 - i], m, 64);
        #pragma unroll
        for (int i = 0; i < 16; ++i) A[i] = umn(A[i], P[i]);
        clean16(A);
    }

    // Epilogue: lane (g,col) writes int4 #g of src and dst for its query.
    const int base = seg * L_SEG;
    const int q    = base + qloc;
    uint32_t r[4];
    #pragma unroll
    for (int v = 0; v < 4; ++v) {  // static select of A[4g+v]
        uint32_t t01 = (g & 1) ? A[4 + v]  : A[v];
        uint32_t t23 = (g & 1) ? A[12 + v] : A[8 + v];
        r[v] = (g & 2) ? t23 : t01;
    }
    int4 sv;
    sv.x = base + (int)(r[0] & 1023u);
    sv.y = base + (int)(r[1] & 1023u);
    sv.z = base + (int)(r[2] & 1023u);
    sv.w = base + (int)(r[3] & 1023u);
    ((int4*)out)[(size_t)q * 4 + g] = sv;
    ((int4*)out)[(size_t)M_PTS * 4 + (size_t)q * 4 + g] = make_int4(q, q, q, q);
}

extern "C" void kernel_launch(void* const* d_in, const int* in_sizes, int n_in,
                              void* d_out, int out_size, void* d_ws, size_t ws_size,
                              hipStream_t stream) {
    const float* x = (const float*)d_in[0];
    // d_in[1] = segs (int64, all 1024) — static per problem setup, unused.
    int* out = (int*)d_out;
    (void)d_ws; (void)ws_size;
    knn_v6_kernel<<<dim3(1024), dim3(256), 0, stream>>>(x, out);
}